// Round 1
// baseline (1390.554 us; speedup 1.0000x reference)
//
#include <hip/hip_runtime.h>
#include <cstdint>
#include <cstddef>

typedef unsigned short u16;
typedef unsigned int   u32;
typedef __attribute__((ext_vector_type(8))) short v8s;   // 8 bf16 (4 VGPRs) MFMA A/B frag
typedef __attribute__((ext_vector_type(4))) float v4f;   // 4 fp32 MFMA C/D frag

// Fixed problem shape
#define B_   2
#define N_   2048
#define C_   1024
#define H_   16
#define D_   64
#define HID_ 4096
#define M_   4096   // B_*N_

static __device__ __forceinline__ float b2f(u32 u) {
    union { u32 i; float f; } x; x.i = u << 16; return x.f;
}
static __device__ __forceinline__ u16 f2b(float f) {
    union { float f; u32 i; } x; x.f = f;
    u32 r = (x.i + 0x7fffu + ((x.i >> 16) & 1u)) >> 16;
    return (u16)r;
}

// ---------------- weight transpose + fp32->bf16 convert: in (K,N) -> out (N,K) ----------------
__global__ __launch_bounds__(256) void transpose_cvt(const float* __restrict__ in,
                                                     u16* __restrict__ out, int K, int N) {
    __shared__ float tile[32][33];
    const int n0 = blockIdx.x * 32, k0 = blockIdx.y * 32;
    const int c = threadIdx.x & 31, r8 = threadIdx.x >> 5;
#pragma unroll
    for (int i = 0; i < 4; ++i)
        tile[r8 + i * 8][c] = in[(size_t)(k0 + r8 + i * 8) * N + n0 + c];
    __syncthreads();
#pragma unroll
    for (int i = 0; i < 4; ++i)
        out[(size_t)(n0 + r8 + i * 8) * K + k0 + c] = f2b(tile[c][r8 + i * 8]);
}

// ---------------- LayerNorm: fp32 in -> bf16 out, one block per row (C=1024) ----------------
__global__ __launch_bounds__(256) void ln_kernel(const float* __restrict__ in,
                                                 const float* __restrict__ g,
                                                 const float* __restrict__ b,
                                                 u16* __restrict__ out) {
    __shared__ float ps[4], psq[4];
    __shared__ float stats[2];
    const int row = blockIdx.x;
    const int t = threadIdx.x;
    float4 v = ((const float4*)in)[(size_t)row * 256 + t];
    float s  = v.x + v.y + v.z + v.w;
    float sq = v.x * v.x + v.y * v.y + v.z * v.z + v.w * v.w;
#pragma unroll
    for (int off = 32; off > 0; off >>= 1) { s += __shfl_down(s, off); sq += __shfl_down(sq, off); }
    if ((t & 63) == 0) { ps[t >> 6] = s; psq[t >> 6] = sq; }
    __syncthreads();
    if (t == 0) {
        float S = ps[0] + ps[1] + ps[2] + ps[3];
        float Q = psq[0] + psq[1] + psq[2] + psq[3];
        float mu  = S * (1.f / 1024.f);
        float var = Q * (1.f / 1024.f) - mu * mu;
        stats[0] = mu; stats[1] = rsqrtf(var + 1e-5f);
    }
    __syncthreads();
    const float mu = stats[0], istd = stats[1];
    float4 gg = ((const float4*)g)[t];
    float4 bb = ((const float4*)b)[t];
    ushort4 o;
    o.x = f2b((v.x - mu) * istd * gg.x + bb.x);
    o.y = f2b((v.y - mu) * istd * gg.y + bb.y);
    o.z = f2b((v.z - mu) * istd * gg.z + bb.z);
    o.w = f2b((v.w - mu) * istd * gg.w + bb.w);
    *(ushort4*)&out[(size_t)row * 1024 + t * 4] = o;
}

// ---------------- RoPE table: tab[n*32+d] = (cos, sin) of n * 10000^(-d/32) ----------------
__global__ __launch_bounds__(256) void rope_table(float2* __restrict__ tab) {
    const int i = blockIdx.x * 256 + threadIdx.x;   // 65536 total
    const int d = i & 31, n = i >> 5;
    float inv = powf(10000.f, -(float)d * (1.f / 32.f));
    float fr = (float)n * inv;
    tab[i] = make_float2(cosf(fr), sinf(fr));
}

// ---------------- RoPE apply in-place on q,k halves of qkv buffer (3,B,H,N,D) bf16 ----------------
__global__ __launch_bounds__(256) void rope_apply(u16* __restrict__ qk, const float2* __restrict__ tab) {
    const int i = blockIdx.x * 256 + threadIdx.x;   // pair index over q and k
    const int hd = i & 31;
    const int n  = (i >> 5) & 2047;
    float2 cs = tab[n * 32 + hd];
    u32 raw = *(u32*)&qk[(size_t)i * 2];
    float x1 = b2f(raw & 0xffffu), x2 = b2f(raw >> 16);
    float r1 = x1 * cs.x - x2 * cs.y;
    float r2 = x1 * cs.y + x2 * cs.x;
    *(u32*)&qk[(size_t)i * 2] = (u32)f2b(r1) | ((u32)f2b(r2) << 16);
}

// ---------------- MFMA GEMM: A (M,K) bf16 row-major, Bt (N,K) bf16 row-major ----------------
// 128x128 tile, BK=32, 4 waves (2x2), 4x4 16x16x32 frags per wave.
// EPI: 0 = qkv scatter to (3,B,H,N,D) bf16; 1 = fp32 out + bias + residual; 2 = GELU -> bf16
template <int EPI>
__global__ __launch_bounds__(256) void gemm_bt(const u16* __restrict__ A,
                                               const u16* __restrict__ Bt,
                                               const float* __restrict__ bias,
                                               void* __restrict__ outp,
                                               const float* __restrict__ resid,
                                               int Ndim, int Kdim) {
    __shared__ u16 As[128 * 32];
    __shared__ u16 Bs[128 * 32];
    const int t = threadIdx.x;
    const int lane = t & 63;
    const int w = t >> 6;
    const int wr = w >> 1, wc = w & 1;
    const int m0 = blockIdx.y * 128, n0 = blockIdx.x * 128;
    const int hi = lane >> 4, lo = lane & 15;

    const v4f vzero = {0.f, 0.f, 0.f, 0.f};
    v4f acc[4][4];
#pragma unroll
    for (int i = 0; i < 4; ++i)
#pragma unroll
        for (int j = 0; j < 4; ++j) acc[i][j] = vzero;

    for (int kt = 0; kt < Kdim; kt += 32) {
#pragma unroll
        for (int i = 0; i < 2; ++i) {
            const int chunk = i * 256 + t;
            const int row = chunk >> 2;
            const int col = (chunk & 3) * 8;
            *(uint4*)&As[chunk * 8] = *(const uint4*)&A[(size_t)(m0 + row) * Kdim + kt + col];
            *(uint4*)&Bs[chunk * 8] = *(const uint4*)&Bt[(size_t)(n0 + row) * Kdim + kt + col];
        }
        __syncthreads();
        v8s av[4], bv[4];
#pragma unroll
        for (int mi = 0; mi < 4; ++mi)
            av[mi] = *(const v8s*)&As[(wr * 64 + mi * 16 + lo) * 32 + hi * 8];
#pragma unroll
        for (int ni = 0; ni < 4; ++ni)
            bv[ni] = *(const v8s*)&Bs[(wc * 64 + ni * 16 + lo) * 32 + hi * 8];
#pragma unroll
        for (int mi = 0; mi < 4; ++mi)
#pragma unroll
            for (int ni = 0; ni < 4; ++ni)
                acc[mi][ni] = __builtin_amdgcn_mfma_f32_16x16x32_bf16(av[mi], bv[ni], acc[mi][ni], 0, 0, 0);
        __syncthreads();
    }

#pragma unroll
    for (int mi = 0; mi < 4; ++mi)
#pragma unroll
        for (int ni = 0; ni < 4; ++ni) {
            const int col = n0 + wc * 64 + ni * 16 + lo;
            const float bsv = bias[col];
#pragma unroll
            for (int r = 0; r < 4; ++r) {
                const int row = m0 + wr * 64 + mi * 16 + hi * 4 + r;
                float vacc = acc[mi][ni][r] + bsv;
                if (EPI == 0) {
                    const int s = col >> 10, rem = col & 1023, hh = rem >> 6, dd = rem & 63;
                    const int bb = row >> 11, nn = row & 2047;
                    ((u16*)outp)[((((size_t)s * B_ + bb) * H_ + hh) * N_ + nn) * D_ + dd] = f2b(vacc);
                } else if (EPI == 1) {
                    ((float*)outp)[(size_t)row * Ndim + col] = vacc + resid[(size_t)row * Ndim + col];
                } else {
                    const float gv = 0.5f * vacc * (1.f + erff(vacc * 0.70710678118f));
                    ((u16*)outp)[(size_t)row * Ndim + col] = f2b(gv);
                }
            }
        }
}

// ---------------- attention: vector flash, fp32 LDS. block = 4 waves, 16 q rows, KV tiles of 64 ----------------
__global__ __launch_bounds__(256) void attn_kernel(const u16* __restrict__ q,
                                                   const u16* __restrict__ k,
                                                   const u16* __restrict__ v,
                                                   u16* __restrict__ out) {
    __shared__ float Ks[64][68];
    __shared__ float Vs[64][68];
    __shared__ float q_s[16][64];
    __shared__ float p_s[4][64][4];

    const int t = threadIdx.x;
    const int w = t >> 6;
    const int lane = t & 63;
    const int bh = blockIdx.y;
    const int r0 = blockIdx.x * 16;

    const u16* qb = q + (size_t)bh * N_ * D_;
    const u16* kb = k + (size_t)bh * N_ * D_;
    const u16* vb = v + (size_t)bh * N_ * D_;

    {   // stage q rows, pre-scaled by 1/sqrt(D)
        const int row = t >> 4, col = (t & 15) * 4;
        ushort4 qr = *(const ushort4*)&qb[(size_t)(r0 + row) * D_ + col];
        q_s[row][col + 0] = b2f(qr.x) * 0.125f;
        q_s[row][col + 1] = b2f(qr.y) * 0.125f;
        q_s[row][col + 2] = b2f(qr.z) * 0.125f;
        q_s[row][col + 3] = b2f(qr.w) * 0.125f;
    }

    const int myrow = w * 4;            // this wave's 4 local q rows
    const int g = lane >> 4, c = lane & 15;
    float4 acc[4];
    float mrun[4], lrun[4];
#pragma unroll
    for (int r = 0; r < 4; ++r) { acc[r] = make_float4(0.f, 0.f, 0.f, 0.f); mrun[r] = -1e30f; lrun[r] = 0.f; }

    for (int kt = 0; kt < N_ / 64; ++kt) {
        __syncthreads();                // prior tile's Vs reads done (also orders q_s stage)
#pragma unroll
        for (int i = 0; i < 2; ++i) {   // stage K,V tile (64x64 bf16 -> fp32, pad 68)
            const int chunk = i * 256 + t;
            const int row = chunk >> 3;
            const int col8 = (chunk & 7) * 8;
            const size_t goff = (size_t)(kt * 64 + row) * D_ + col8;
            uint4 ra = *(const uint4*)&kb[goff];
            uint4 rv = *(const uint4*)&vb[goff];
            float* kd = &Ks[row][col8];
            float* vd = &Vs[row][col8];
            kd[0] = b2f(ra.x & 0xffffu); kd[1] = b2f(ra.x >> 16);
            kd[2] = b2f(ra.y & 0xffffu); kd[3] = b2f(ra.y >> 16);
            kd[4] = b2f(ra.z & 0xffffu); kd[5] = b2f(ra.z >> 16);
            kd[6] = b2f(ra.w & 0xffffu); kd[7] = b2f(ra.w >> 16);
            vd[0] = b2f(rv.x & 0xffffu); vd[1] = b2f(rv.x >> 16);
            vd[2] = b2f(rv.y & 0xffffu); vd[3] = b2f(rv.y >> 16);
            vd[4] = b2f(rv.z & 0xffffu); vd[5] = b2f(rv.z >> 16);
            vd[6] = b2f(rv.w & 0xffffu); vd[7] = b2f(rv.w >> 16);
        }
        __syncthreads();

        float sc[4] = {0.f, 0.f, 0.f, 0.f};   // this lane's key = lane
#pragma unroll
        for (int d4 = 0; d4 < 16; ++d4) {
            float4 kv = *(const float4*)&Ks[lane][d4 * 4];
#pragma unroll
            for (int r = 0; r < 4; ++r) {
                float4 qv = *(const float4*)&q_s[myrow + r][d4 * 4];
                sc[r] += qv.x * kv.x + qv.y * kv.y + qv.z * kv.z + qv.w * kv.w;
            }
        }

#pragma unroll
        for (int r = 0; r < 4; ++r) {   // online softmax update (wave-uniform m, l)
            float tmax = sc[r];
#pragma unroll
            for (int off = 32; off > 0; off >>= 1) tmax = fmaxf(tmax, __shfl_xor(tmax, off));
            float mn = fmaxf(mrun[r], tmax);
            float al = __expf(mrun[r] - mn);
            mrun[r] = mn;
            float pp = __expf(sc[r] - mn);
            sc[r] = pp;
            float psum = pp;
#pragma unroll
            for (int off = 32; off > 0; off >>= 1) psum += __shfl_xor(psum, off);
            lrun[r] = lrun[r] * al + psum;
            acc[r].x *= al; acc[r].y *= al; acc[r].z *= al; acc[r].w *= al;
        }
        *(float4*)&p_s[w][lane][0] = make_float4(sc[0], sc[1], sc[2], sc[3]);

#pragma unroll
        for (int jj = 0; jj < 16; ++jj) {   // PV: lane-group g owns keys j = 4*jj+g, dims 4c..4c+3
            const int j = jj * 4 + g;
            float4 pv = *(const float4*)&p_s[w][j][0];
            float4 vv = *(const float4*)&Vs[j][c * 4];
            acc[0].x += pv.x * vv.x; acc[0].y += pv.x * vv.y; acc[0].z += pv.x * vv.z; acc[0].w += pv.x * vv.w;
            acc[1].x += pv.y * vv.x; acc[1].y += pv.y * vv.y; acc[1].z += pv.y * vv.z; acc[1].w += pv.y * vv.w;
            acc[2].x += pv.z * vv.x; acc[2].y += pv.z * vv.y; acc[2].z += pv.z * vv.z; acc[2].w += pv.z * vv.w;
            acc[3].x += pv.w * vv.x; acc[3].y += pv.w * vv.y; acc[3].z += pv.w * vv.z; acc[3].w += pv.w * vv.w;
        }
    }

    const int bb = bh >> 4, hh = bh & 15;
#pragma unroll
    for (int r = 0; r < 4; ++r) {
        float4 a4 = acc[r];
        a4.x += __shfl_xor(a4.x, 16); a4.y += __shfl_xor(a4.y, 16);
        a4.z += __shfl_xor(a4.z, 16); a4.w += __shfl_xor(a4.w, 16);
        a4.x += __shfl_xor(a4.x, 32); a4.y += __shfl_xor(a4.y, 32);
        a4.z += __shfl_xor(a4.z, 32); a4.w += __shfl_xor(a4.w, 32);
        if (lane < 16) {
            const float inv = 1.f / lrun[r];
            const size_t off = ((size_t)bb * N_ + (r0 + myrow + r)) * C_ + hh * D_ + c * 4;
            ushort4 ob;
            ob.x = f2b(a4.x * inv); ob.y = f2b(a4.y * inv);
            ob.z = f2b(a4.z * inv); ob.w = f2b(a4.w * inv);
            *(ushort4*)&out[off] = ob;
        }
    }
}

// ---------------- orchestration ----------------
extern "C" void kernel_launch(void* const* d_in, const int* in_sizes, int n_in,
                              void* d_out, int out_size, void* d_ws, size_t ws_size,
                              hipStream_t stream) {
    (void)in_sizes; (void)n_in; (void)out_size; (void)ws_size;
    const float* x     = (const float*)d_in[0];
    const float* ln1g  = (const float*)d_in[1];
    const float* ln1b  = (const float*)d_in[2];
    const float* Wqkv  = (const float*)d_in[3];
    const float* bqkv  = (const float*)d_in[4];
    const float* Wproj = (const float*)d_in[5];
    const float* bproj = (const float*)d_in[6];
    const float* ln2g  = (const float*)d_in[7];
    const float* ln2b  = (const float*)d_in[8];
    const float* Wfc1  = (const float*)d_in[9];
    const float* bfc1  = (const float*)d_in[10];
    const float* Wfc2  = (const float*)d_in[11];
    const float* bfc2  = (const float*)d_in[12];
    float* out = (float*)d_out;

    char* p = (char*)d_ws;
    auto alloc = [&](size_t bytes) -> char* {
        char* r = p; p += (bytes + 255) & ~(size_t)255; return r;
    };
    u16*    h1     = (u16*)alloc((size_t)M_ * C_ * 2);        // LN1 out bf16
    u16*    Wtqkv  = (u16*)alloc((size_t)3 * C_ * C_ * 2);    // (3C, C)
    u16*    Wtproj = (u16*)alloc((size_t)C_ * C_ * 2);        // (C, C)
    u16*    Wtfc1  = (u16*)alloc((size_t)HID_ * C_ * 2);      // (HID, C)
    u16*    Wtfc2  = (u16*)alloc((size_t)C_ * HID_ * 2);      // (C, HID)
    u16*    qkv    = (u16*)alloc((size_t)3 * M_ * C_ * 2);    // (3,B,H,N,D) bf16
    float2* tab    = (float2*)alloc((size_t)N_ * (D_ / 2) * sizeof(float2));
    u16*    oatt   = (u16*)alloc((size_t)M_ * C_ * 2);        // attn out (B,N,C) bf16
    float*  x1     = (float*)alloc((size_t)M_ * C_ * 4);      // residual after attn, fp32
    u16*    h2     = (u16*)alloc((size_t)M_ * C_ * 2);        // LN2 out bf16
    u16*    a1     = (u16*)alloc((size_t)M_ * HID_ * 2);      // gelu(fc1) bf16

    transpose_cvt<<<dim3(3 * C_ / 32, C_ / 32), 256, 0, stream>>>(Wqkv, Wtqkv, C_, 3 * C_);
    transpose_cvt<<<dim3(C_ / 32, C_ / 32), 256, 0, stream>>>(Wproj, Wtproj, C_, C_);
    transpose_cvt<<<dim3(HID_ / 32, C_ / 32), 256, 0, stream>>>(Wfc1, Wtfc1, C_, HID_);
    transpose_cvt<<<dim3(C_ / 32, HID_ / 32), 256, 0, stream>>>(Wfc2, Wtfc2, HID_, C_);
    rope_table<<<N_ * (D_ / 2) / 256, 256, 0, stream>>>(tab);
    ln_kernel<<<M_, 256, 0, stream>>>(x, ln1g, ln1b, h1);
    gemm_bt<0><<<dim3(3 * C_ / 128, M_ / 128), 256, 0, stream>>>(h1, Wtqkv, bqkv, qkv, nullptr, 3 * C_, C_);
    rope_apply<<<2 * B_ * H_ * N_ * (D_ / 2) / 256, 256, 0, stream>>>(qkv, tab);
    attn_kernel<<<dim3(N_ / 16, B_ * H_), 256, 0, stream>>>(
        qkv, qkv + (size_t)B_ * H_ * N_ * D_, qkv + (size_t)2 * B_ * H_ * N_ * D_, oatt);
    gemm_bt<1><<<dim3(C_ / 128, M_ / 128), 256, 0, stream>>>(oatt, Wtproj, bproj, x1, x, C_, C_);
    ln_kernel<<<M_, 256, 0, stream>>>(x1, ln2g, ln2b, h2);
    gemm_bt<2><<<dim3(HID_ / 128, M_ / 128), 256, 0, stream>>>(h2, Wtfc1, bfc1, a1, nullptr, HID_, C_);
    gemm_bt<1><<<dim3(C_ / 128, M_ / 128), 256, 0, stream>>>(a1, Wtfc2, bfc2, out, x1, C_, HID_);
}

// Round 2
// 413.000 us; speedup vs baseline: 3.3670x; 3.3670x over previous
//
#include <hip/hip_runtime.h>
#include <cstdint>
#include <cstddef>

typedef unsigned short u16;
typedef unsigned int   u32;
typedef __attribute__((ext_vector_type(8))) short v8s;   // 8 bf16 (4 VGPRs) MFMA A/B frag
typedef __attribute__((ext_vector_type(4))) float v4f;   // 4 fp32 MFMA C/D frag

// Fixed problem shape
#define B_   2
#define N_   2048
#define C_   1024
#define H_   16
#define D_   64
#define HID_ 4096
#define M_   4096   // B_*N_

static __device__ __forceinline__ float b2f(u32 u) {
    union { u32 i; float f; } x; x.i = u << 16; return x.f;
}
static __device__ __forceinline__ u16 f2b(float f) {
    union { float f; u32 i; } x; x.f = f;
    u32 r = (x.i + 0x7fffu + ((x.i >> 16) & 1u)) >> 16;
    return (u16)r;
}
static __device__ __forceinline__ u32 scale2(u32 raw, float s) {
    float lo = b2f(raw & 0xffffu) * s, hi = b2f(raw >> 16) * s;
    return (u32)f2b(lo) | ((u32)f2b(hi) << 16);
}

// ---------------- weight transpose + fp32->bf16 convert: in (K,N) -> out (N,K) ----------------
__global__ __launch_bounds__(256) void transpose_cvt(const float* __restrict__ in,
                                                     u16* __restrict__ out, int K, int N) {
    __shared__ float tile[32][33];
    const int n0 = blockIdx.x * 32, k0 = blockIdx.y * 32;
    const int c = threadIdx.x & 31, r8 = threadIdx.x >> 5;
#pragma unroll
    for (int i = 0; i < 4; ++i)
        tile[r8 + i * 8][c] = in[(size_t)(k0 + r8 + i * 8) * N + n0 + c];
    __syncthreads();
#pragma unroll
    for (int i = 0; i < 4; ++i)
        out[(size_t)(n0 + r8 + i * 8) * K + k0 + c] = f2b(tile[c][r8 + i * 8]);
}

// ---------------- LayerNorm: fp32 in -> bf16 out, one block per row (C=1024) ----------------
__global__ __launch_bounds__(256) void ln_kernel(const float* __restrict__ in,
                                                 const float* __restrict__ g,
                                                 const float* __restrict__ b,
                                                 u16* __restrict__ out) {
    __shared__ float ps[4], psq[4];
    __shared__ float stats[2];
    const int row = blockIdx.x;
    const int t = threadIdx.x;
    float4 v = ((const float4*)in)[(size_t)row * 256 + t];
    float s  = v.x + v.y + v.z + v.w;
    float sq = v.x * v.x + v.y * v.y + v.z * v.z + v.w * v.w;
#pragma unroll
    for (int off = 32; off > 0; off >>= 1) { s += __shfl_down(s, off); sq += __shfl_down(sq, off); }
    if ((t & 63) == 0) { ps[t >> 6] = s; psq[t >> 6] = sq; }
    __syncthreads();
    if (t == 0) {
        float S = ps[0] + ps[1] + ps[2] + ps[3];
        float Q = psq[0] + psq[1] + psq[2] + psq[3];
        float mu  = S * (1.f / 1024.f);
        float var = Q * (1.f / 1024.f) - mu * mu;
        stats[0] = mu; stats[1] = rsqrtf(var + 1e-5f);
    }
    __syncthreads();
    const float mu = stats[0], istd = stats[1];
    float4 gg = ((const float4*)g)[t];
    float4 bb = ((const float4*)b)[t];
    ushort4 o;
    o.x = f2b((v.x - mu) * istd * gg.x + bb.x);
    o.y = f2b((v.y - mu) * istd * gg.y + bb.y);
    o.z = f2b((v.z - mu) * istd * gg.z + bb.z);
    o.w = f2b((v.w - mu) * istd * gg.w + bb.w);
    *(ushort4*)&out[(size_t)row * 1024 + t * 4] = o;
}

// ---------------- RoPE table: tab[n*32+d] = (cos, sin) of n * 10000^(-d/32) ----------------
__global__ __launch_bounds__(256) void rope_table(float2* __restrict__ tab) {
    const int i = blockIdx.x * 256 + threadIdx.x;   // 65536 total
    const int d = i & 31, n = i >> 5;
    float inv = powf(10000.f, -(float)d * (1.f / 32.f));
    float fr = (float)n * inv;
    tab[i] = make_float2(cosf(fr), sinf(fr));
}

// ---------------- RoPE apply in-place on q,k halves of qkv buffer (3,B,H,N,D) bf16 ----------------
__global__ __launch_bounds__(256) void rope_apply(u16* __restrict__ qk, const float2* __restrict__ tab) {
    const int i = blockIdx.x * 256 + threadIdx.x;   // pair index over q and k
    const int hd = i & 31;
    const int n  = (i >> 5) & 2047;
    float2 cs = tab[n * 32 + hd];
    u32 raw = *(u32*)&qk[(size_t)i * 2];
    float x1 = b2f(raw & 0xffffu), x2 = b2f(raw >> 16);
    float r1 = x1 * cs.x - x2 * cs.y;
    float r2 = x1 * cs.y + x2 * cs.x;
    *(u32*)&qk[(size_t)i * 2] = (u32)f2b(r1) | ((u32)f2b(r2) << 16);
}

// ---------------- MFMA GEMM: A (M,K) bf16 row-major, Bt (N,K) bf16 row-major ----------------
template <int EPI>
__global__ __launch_bounds__(256) void gemm_bt(const u16* __restrict__ A,
                                               const u16* __restrict__ Bt,
                                               const float* __restrict__ bias,
                                               void* __restrict__ outp,
                                               const float* __restrict__ resid,
                                               int Ndim, int Kdim) {
    __shared__ u16 As[128 * 32];
    __shared__ u16 Bs[128 * 32];
    const int t = threadIdx.x;
    const int lane = t & 63;
    const int w = t >> 6;
    const int wr = w >> 1, wc = w & 1;
    const int m0 = blockIdx.y * 128, n0 = blockIdx.x * 128;
    const int hi = lane >> 4, lo = lane & 15;

    const v4f vzero = {0.f, 0.f, 0.f, 0.f};
    v4f acc[4][4];
#pragma unroll
    for (int i = 0; i < 4; ++i)
#pragma unroll
        for (int j = 0; j < 4; ++j) acc[i][j] = vzero;

    for (int kt = 0; kt < Kdim; kt += 32) {
#pragma unroll
        for (int i = 0; i < 2; ++i) {
            const int chunk = i * 256 + t;
            const int row = chunk >> 2;
            const int col = (chunk & 3) * 8;
            *(uint4*)&As[chunk * 8] = *(const uint4*)&A[(size_t)(m0 + row) * Kdim + kt + col];
            *(uint4*)&Bs[chunk * 8] = *(const uint4*)&Bt[(size_t)(n0 + row) * Kdim + kt + col];
        }
        __syncthreads();
        v8s av[4], bv[4];
#pragma unroll
        for (int mi = 0; mi < 4; ++mi)
            av[mi] = *(const v8s*)&As[(wr * 64 + mi * 16 + lo) * 32 + hi * 8];
#pragma unroll
        for (int ni = 0; ni < 4; ++ni)
            bv[ni] = *(const v8s*)&Bs[(wc * 64 + ni * 16 + lo) * 32 + hi * 8];
#pragma unroll
        for (int mi = 0; mi < 4; ++mi)
#pragma unroll
            for (int ni = 0; ni < 4; ++ni)
                acc[mi][ni] = __builtin_amdgcn_mfma_f32_16x16x32_bf16(av[mi], bv[ni], acc[mi][ni], 0, 0, 0);
        __syncthreads();
    }

#pragma unroll
    for (int mi = 0; mi < 4; ++mi)
#pragma unroll
        for (int ni = 0; ni < 4; ++ni) {
            const int col = n0 + wc * 64 + ni * 16 + lo;
            const float bsv = bias[col];
#pragma unroll
            for (int r = 0; r < 4; ++r) {
                const int row = m0 + wr * 64 + mi * 16 + hi * 4 + r;
                float vacc = acc[mi][ni][r] + bsv;
                if (EPI == 0) {
                    const int s = col >> 10, rem = col & 1023, hh = rem >> 6, dd = rem & 63;
                    const int bb = row >> 11, nn = row & 2047;
                    ((u16*)outp)[((((size_t)s * B_ + bb) * H_ + hh) * N_ + nn) * D_ + dd] = f2b(vacc);
                } else if (EPI == 1) {
                    ((float*)outp)[(size_t)row * Ndim + col] = vacc + resid[(size_t)row * Ndim + col];
                } else {
                    const float gv = 0.5f * vacc * (1.f + erff(vacc * 0.70710678118f));
                    ((u16*)outp)[(size_t)row * Ndim + col] = f2b(gv);
                }
            }
        }
}

// ---------------- MFMA flash attention ----------------
// Block: 4 waves, each wave owns 32 q-rows (2 x 16-row MFMA strips). 128 q-rows/block.
// KV tile = 64. K in LDS [key][dim] XOR-swizzled; V in LDS transposed [dim][key] XOR-swizzled.
// Softmax in exp2 domain (Q pre-scaled by 0.125*log2e), wave-parallel over 16-lane row groups.
#define SCL_LOG2E 0.1803368801111244f   // (1/sqrt(64)) * log2(e)

__global__ __launch_bounds__(256) void attn_mfma(const u16* __restrict__ q,
                                                 const u16* __restrict__ k,
                                                 const u16* __restrict__ v,
                                                 u16* __restrict__ out) {
    __shared__ u16 Ks[64 * 64];       // [key][dim], elem = key*64 + (d ^ ((key&7)<<3))
    __shared__ u16 Vt[64 * 64];       // [dim][key], elem = dim*64 + (key ^ ((dim&7)<<3))
    __shared__ u16 Ps[4][32 * 64];    // per-wave P, elem = row*64 + (key ^ ((row&7)<<3))

    const int t    = threadIdx.x;
    const int w    = t >> 6;
    const int lane = t & 63;
    const int hi   = lane >> 4;
    const int lo   = lane & 15;
    const int bh   = blockIdx.y;
    const int r0g  = blockIdx.x * 128 + w * 32;     // this wave's global q-row base

    const u16* qb = q + (size_t)bh * N_ * D_;
    const u16* kb = k + (size_t)bh * N_ * D_;
    const u16* vb = v + (size_t)bh * N_ * D_;

    // ---- Q A-frags in registers, pre-scaled by 0.125*log2e ----
    v8s qa[2][2];   // [mi][ks]
#pragma unroll
    for (int mi = 0; mi < 2; ++mi)
#pragma unroll
        for (int ks = 0; ks < 2; ++ks) {
            uint4 rq = *(const uint4*)&qb[(size_t)(r0g + mi * 16 + lo) * 64 + ks * 32 + hi * 8];
            u32 qs[4];
            qs[0] = scale2(rq.x, SCL_LOG2E); qs[1] = scale2(rq.y, SCL_LOG2E);
            qs[2] = scale2(rq.z, SCL_LOG2E); qs[3] = scale2(rq.w, SCL_LOG2E);
            qa[mi][ks] = *(v8s*)qs;
        }

    const v4f vzero = {0.f, 0.f, 0.f, 0.f};
    v4f o_acc[2][4];                  // [mi][ni(dim)] -> rows hi*4+r, dims lo+16ni
    float mrun[2][4], lrun[2][4];
#pragma unroll
    for (int mi = 0; mi < 2; ++mi)
#pragma unroll
        for (int r = 0; r < 4; ++r) { mrun[mi][r] = -1e30f; lrun[mi][r] = 0.f; }
#pragma unroll
    for (int mi = 0; mi < 2; ++mi)
#pragma unroll
        for (int ni = 0; ni < 4; ++ni) o_acc[mi][ni] = vzero;

    // V-stage thread mapping: key-pair p, dim-group g
    const int vp = t & 31, vg = t >> 5;             // p: 0..31, g: 0..7
    const int vd0 = vg * 8, vkey = vp * 2;

    for (int kt = 0; kt < N_ / 64; ++kt) {
        __syncthreads();              // prior tile's LDS reads complete
        // ---- stage K tile ----
#pragma unroll
        for (int i = 0; i < 2; ++i) {
            const int chunk = i * 256 + t;
            const int key = chunk >> 3, d0 = (chunk & 7) * 8;
            uint4 raw = *(const uint4*)&kb[(size_t)(kt * 64 + key) * 64 + d0];
            *(uint4*)&Ks[key * 64 + (d0 ^ ((key & 7) << 3))] = raw;
        }
        // ---- stage V tile transposed (pairs of keys per b32 write) ----
        {
            uint4 r0 = *(const uint4*)&vb[(size_t)(kt * 64 + vkey) * 64 + vd0];
            uint4 r1 = *(const uint4*)&vb[(size_t)(kt * 64 + vkey + 1) * 64 + vd0];
            const u32* a0 = (const u32*)&r0;
            const u32* a1 = (const u32*)&r1;
#pragma unroll
            for (int j = 0; j < 8; ++j) {
                u32 lo16 = (j & 1) ? (a0[j >> 1] >> 16) : (a0[j >> 1] & 0xffffu);
                u32 hi16 = (j & 1) ? (a1[j >> 1] >> 16) : (a1[j >> 1] & 0xffffu);
                u32 val = lo16 | (hi16 << 16);
                *(u32*)&Vt[(vd0 + j) * 64 + (vkey ^ (j << 3))] = val;
            }
        }
        __syncthreads();

        // ---- QK^T: S[mi][ni] ----
        v4f s[2][4];
#pragma unroll
        for (int mi = 0; mi < 2; ++mi)
#pragma unroll
            for (int ni = 0; ni < 4; ++ni) s[mi][ni] = vzero;
#pragma unroll
        for (int ks = 0; ks < 2; ++ks)
#pragma unroll
            for (int ni = 0; ni < 4; ++ni) {
                const int key = lo + 16 * ni;
                v8s bv = *(const v8s*)&Ks[key * 64 + ((ks * 32 + hi * 8) ^ ((key & 7) << 3))];
                s[0][ni] = __builtin_amdgcn_mfma_f32_16x16x32_bf16(qa[0][ks], bv, s[0][ni], 0, 0, 0);
                s[1][ni] = __builtin_amdgcn_mfma_f32_16x16x32_bf16(qa[1][ks], bv, s[1][ni], 0, 0, 0);
            }

        // ---- online softmax (exp2 domain), rows = hi*4+r per mi strip ----
#pragma unroll
        for (int mi = 0; mi < 2; ++mi)
#pragma unroll
            for (int r = 0; r < 4; ++r) {
                float mx = fmaxf(fmaxf(s[mi][0][r], s[mi][1][r]), fmaxf(s[mi][2][r], s[mi][3][r]));
#pragma unroll
                for (int off = 1; off < 16; off <<= 1) mx = fmaxf(mx, __shfl_xor(mx, off));
                float mn = fmaxf(mrun[mi][r], mx);
                float al = exp2f(mrun[mi][r] - mn);
                mrun[mi][r] = mn;
                float psum = 0.f;
#pragma unroll
                for (int ni = 0; ni < 4; ++ni) {
                    float pp = exp2f(s[mi][ni][r] - mn);
                    s[mi][ni][r] = pp;
                    psum += pp;
                }
#pragma unroll
                for (int off = 1; off < 16; off <<= 1) psum += __shfl_xor(psum, off);
                lrun[mi][r] = lrun[mi][r] * al + psum;
#pragma unroll
                for (int ni = 0; ni < 4; ++ni) o_acc[mi][ni][r] *= al;
            }

        // ---- write P (bf16) to per-wave LDS in D-layout, re-read in A-layout ----
#pragma unroll
        for (int mi = 0; mi < 2; ++mi)
#pragma unroll
            for (int f = 0; f < 4; ++f)
#pragma unroll
                for (int r = 0; r < 4; ++r) {
                    const int row = mi * 16 + hi * 4 + r;
                    Ps[w][row * 64 + ((lo + 16 * f) ^ ((row & 7) << 3))] = f2b(s[mi][f][r]);
                }
        v8s pa[2][2];
#pragma unroll
        for (int mi = 0; mi < 2; ++mi)
#pragma unroll
            for (int ks = 0; ks < 2; ++ks) {
                const int row = mi * 16 + lo;
                pa[mi][ks] = *(const v8s*)&Ps[w][row * 64 + ((ks * 32 + hi * 8) ^ ((lo & 7) << 3))];
            }

        // ---- PV: O += P @ V ----
#pragma unroll
        for (int ks = 0; ks < 2; ++ks)
#pragma unroll
            for (int ni = 0; ni < 4; ++ni) {
                const int dim = lo + 16 * ni;
                v8s vv = *(const v8s*)&Vt[dim * 64 + ((ks * 32 + hi * 8) ^ ((dim & 7) << 3))];
                o_acc[0][ni] = __builtin_amdgcn_mfma_f32_16x16x32_bf16(pa[0][ks], vv, o_acc[0][ni], 0, 0, 0);
                o_acc[1][ni] = __builtin_amdgcn_mfma_f32_16x16x32_bf16(pa[1][ks], vv, o_acc[1][ni], 0, 0, 0);
            }
    }

    // ---- epilogue: normalize, store (B,N,C) bf16 ----
    const int bb = bh >> 4, hh = bh & 15;
#pragma unroll
    for (int mi = 0; mi < 2; ++mi)
#pragma unroll
        for (int r = 0; r < 4; ++r) {
            const float inv = 1.f / lrun[mi][r];
            const int n = r0g + mi * 16 + hi * 4 + r;
#pragma unroll
            for (int ni = 0; ni < 4; ++ni) {
                out[((size_t)bb * N_ + n) * C_ + hh * D_ + lo + 16 * ni] = f2b(o_acc[mi][ni][r] * inv);
            }
        }
}

// ---------------- orchestration ----------------
extern "C" void kernel_launch(void* const* d_in, const int* in_sizes, int n_in,
                              void* d_out, int out_size, void* d_ws, size_t ws_size,
                              hipStream_t stream) {
    (void)in_sizes; (void)n_in; (void)out_size; (void)ws_size;
    const float* x     = (const float*)d_in[0];
    const float* ln1g  = (const float*)d_in[1];
    const float* ln1b  = (const float*)d_in[2];
    const float* Wqkv  = (const float*)d_in[3];
    const float* bqkv  = (const float*)d_in[4];
    const float* Wproj = (const float*)d_in[5];
    const float* bproj = (const float*)d_in[6];
    const float* ln2g  = (const float*)d_in[7];
    const float* ln2b  = (const float*)d_in[8];
    const float* Wfc1  = (const float*)d_in[9];
    const float* bfc1  = (const float*)d_in[10];
    const float* Wfc2  = (const float*)d_in[11];
    const float* bfc2  = (const float*)d_in[12];
    float* out = (float*)d_out;

    char* p = (char*)d_ws;
    auto alloc = [&](size_t bytes) -> char* {
        char* r = p; p += (bytes + 255) & ~(size_t)255; return r;
    };
    u16*    h1     = (u16*)alloc((size_t)M_ * C_ * 2);        // LN1 out bf16
    u16*    Wtqkv  = (u16*)alloc((size_t)3 * C_ * C_ * 2);    // (3C, C)
    u16*    Wtproj = (u16*)alloc((size_t)C_ * C_ * 2);        // (C, C)
    u16*    Wtfc1  = (u16*)alloc((size_t)HID_ * C_ * 2);      // (HID, C)
    u16*    Wtfc2  = (u16*)alloc((size_t)C_ * HID_ * 2);      // (C, HID)
    u16*    qkv    = (u16*)alloc((size_t)3 * M_ * C_ * 2);    // (3,B,H,N,D) bf16
    float2* tab    = (float2*)alloc((size_t)N_ * (D_ / 2) * sizeof(float2));
    u16*    oatt   = (u16*)alloc((size_t)M_ * C_ * 2);        // attn out (B,N,C) bf16
    float*  x1     = (float*)alloc((size_t)M_ * C_ * 4);      // residual after attn, fp32
    u16*    h2     = (u16*)alloc((size_t)M_ * C_ * 2);        // LN2 out bf16
    u16*    a1     = (u16*)alloc((size_t)M_ * HID_ * 2);      // gelu(fc1) bf16

    transpose_cvt<<<dim3(3 * C_ / 32, C_ / 32), 256, 0, stream>>>(Wqkv, Wtqkv, C_, 3 * C_);
    transpose_cvt<<<dim3(C_ / 32, C_ / 32), 256, 0, stream>>>(Wproj, Wtproj, C_, C_);
    transpose_cvt<<<dim3(HID_ / 32, C_ / 32), 256, 0, stream>>>(Wfc1, Wtfc1, C_, HID_);
    transpose_cvt<<<dim3(C_ / 32, HID_ / 32), 256, 0, stream>>>(Wfc2, Wtfc2, HID_, C_);
    rope_table<<<N_ * (D_ / 2) / 256, 256, 0, stream>>>(tab);
    ln_kernel<<<M_, 256, 0, stream>>>(x, ln1g, ln1b, h1);
    gemm_bt<0><<<dim3(3 * C_ / 128, M_ / 128), 256, 0, stream>>>(h1, Wtqkv, bqkv, qkv, nullptr, 3 * C_, C_);
    rope_apply<<<2 * B_ * H_ * N_ * (D_ / 2) / 256, 256, 0, stream>>>(qkv, tab);
    attn_mfma<<<dim3(N_ / 128, B_ * H_), 256, 0, stream>>>(
        qkv, qkv + (size_t)B_ * H_ * N_ * D_, qkv + (size_t)2 * B_ * H_ * N_ * D_, oatt);
    gemm_bt<1><<<dim3(C_ / 128, M_ / 128), 256, 0, stream>>>(oatt, Wtproj, bproj, x1, x, C_, C_);
    ln_kernel<<<M_, 256, 0, stream>>>(x1, ln2g, ln2b, h2);
    gemm_bt<2><<<dim3(HID_ / 128, M_ / 128), 256, 0, stream>>>(h2, Wtfc1, bfc1, a1, nullptr, HID_, C_);
    gemm_bt<1><<<dim3(C_ / 128, M_ / 128), 256, 0, stream>>>(a1, Wtfc2, bfc2, out, x1, C_, HID_);
}